// Round 1
// baseline (2256.146 us; speedup 1.0000x reference)
//
#include <hip/hip_runtime.h>
#include <hip/hip_bf16.h>

#define N_NODES 50000
#define N_EDGES 800000
#define N_GRAPHS 256
#define F_IN 310
#define CH 256
#define HID 128

__device__ __forceinline__ float selu_f(float x) {
    const float scale = 1.0507009873554805f;
    const float alpha = 1.6732632423543772f;
    return x > 0.f ? scale * x : scale * alpha * (expm1f(x));
}

__device__ __forceinline__ unsigned enc_f32(float f) {
    unsigned u = __float_as_uint(f);
    return (u & 0x80000000u) ? ~u : (u | 0x80000000u);
}
__device__ __forceinline__ float dec_f32(unsigned u) {
    u = (u & 0x80000000u) ? (u ^ 0x80000000u) : ~u;
    return __uint_as_float(u);
}

// ---------------- GEMM: C[M,N] = A[M,K] @ B[K,N], fp32, tiled ----------------
#define BM 128
#define BN 128
#define BKK 8
#define TM 8
#define TN 8
__global__ __launch_bounds__(256) void gemm_f32(
        const float* __restrict__ A, const float* __restrict__ B,
        float* __restrict__ C, int M, int N, int K) {
    __shared__ float As[BKK][BM + 4];
    __shared__ float Bs[BKK][BN + 4];
    int tid = threadIdx.x;
    int col0 = blockIdx.x * BN;
    int row0 = blockIdx.y * BM;
    int tx = tid & 15, ty = tid >> 4;
    float acc[TM][TN] = {};
    int a_r = tid >> 3;   // 0..31
    int a_k = tid & 7;    // 0..7
    int b_k = tid >> 7;   // 0..1
    int b_c = tid & 127;  // 0..127
    for (int k0 = 0; k0 < K; k0 += BKK) {
#pragma unroll
        for (int i = 0; i < 4; i++) {
            int r = a_r + i * 32;
            int gr = row0 + r, gk = k0 + a_k;
            As[a_k][r] = (gr < M && gk < K) ? A[(long)gr * K + gk] : 0.f;
        }
#pragma unroll
        for (int i = 0; i < 4; i++) {
            int k = b_k + i * 2;
            int gk = k0 + k;
            Bs[k][b_c] = (gk < K) ? B[(long)gk * N + col0 + b_c] : 0.f;
        }
        __syncthreads();
#pragma unroll
        for (int kk = 0; kk < BKK; kk++) {
            float af[TM], bf[TN];
#pragma unroll
            for (int i = 0; i < TM; i++) af[i] = As[kk][ty * TM + i];
#pragma unroll
            for (int j = 0; j < TN; j++) bf[j] = Bs[kk][tx * TN + j];
#pragma unroll
            for (int i = 0; i < TM; i++)
#pragma unroll
                for (int j = 0; j < TN; j++) acc[i][j] += af[i] * bf[j];
        }
        __syncthreads();
    }
#pragma unroll
    for (int i = 0; i < TM; i++) {
        int gr = row0 + ty * TM + i;
        if (gr >= M) continue;
#pragma unroll
        for (int j = 0; j < TN; j++) {
            C[(long)gr * N + col0 + tx * TN + j] = acc[i][j];
        }
    }
}

// --------- per-node attention scalars: a_src = h.att_l, a_dst = h.att_r -----
__global__ __launch_bounds__(256) void att_kernel(
        const float* __restrict__ h, const float* __restrict__ att_l,
        const float* __restrict__ att_r, float* __restrict__ a_src,
        float* __restrict__ a_dst, int n) {
    int wave = (blockIdx.x * blockDim.x + threadIdx.x) >> 6;
    int lane = threadIdx.x & 63;
    if (wave >= n) return;
    float sl = 0.f, sr = 0.f;
#pragma unroll
    for (int c = lane; c < CH; c += 64) {
        float v = h[(long)wave * CH + c];
        sl += v * att_l[c];
        sr += v * att_r[c];
    }
#pragma unroll
    for (int off = 32; off > 0; off >>= 1) {
        sl += __shfl_down(sl, off);
        sr += __shfl_down(sr, off);
    }
    if (lane == 0) { a_src[wave] = sl; a_dst[wave] = sr; }
}

// ---- edges: e = leaky_relu(a_src[s]+a_dst[d]); segment max into m_enc ------
__global__ __launch_bounds__(256) void edge_e_max(
        const int* __restrict__ ei, const float* __restrict__ a_src,
        const float* __restrict__ a_dst, float* __restrict__ e_arr,
        unsigned* __restrict__ m_enc) {
    int eid = blockIdx.x * blockDim.x + threadIdx.x;
    const int ET = N_EDGES + N_NODES;
    if (eid >= ET) return;
    int s, d;
    if (eid < N_EDGES) { s = ei[eid]; d = ei[N_EDGES + eid]; }
    else { s = eid - N_EDGES; d = s; }
    float e = a_src[s] + a_dst[d];
    e = e > 0.f ? e : 0.2f * e;
    e_arr[eid] = e;
    atomicMax(&m_enc[d], enc_f32(e));
}

// ---- edges: ex = exp(e - m[d]); segment sum into denom; e_arr <- ex --------
__global__ __launch_bounds__(256) void edge_exp_sum(
        const int* __restrict__ ei, float* __restrict__ e_arr,
        const unsigned* __restrict__ m_enc, float* __restrict__ denom) {
    int eid = blockIdx.x * blockDim.x + threadIdx.x;
    const int ET = N_EDGES + N_NODES;
    if (eid >= ET) return;
    int d = (eid < N_EDGES) ? ei[N_EDGES + eid] : eid - N_EDGES;
    float ex = expf(e_arr[eid] - dec_f32(m_enc[d]));
    e_arr[eid] = ex;
    atomicAdd(&denom[d], ex);
}

// ---- aggregation: out[d] += alpha * h[s], one wave per edge ----------------
__global__ __launch_bounds__(256) void edge_aggregate(
        const int* __restrict__ ei, const float* __restrict__ ex_arr,
        const float* __restrict__ denom, const float* __restrict__ h,
        float* __restrict__ out) {
    int gwave = (int)(((long)blockIdx.x * blockDim.x + threadIdx.x) >> 6);
    int lane = threadIdx.x & 63;
    const int ET = N_EDGES + N_NODES;
    if (gwave >= ET) return;
    int s, d;
    if (gwave < N_EDGES) { s = ei[gwave]; d = ei[N_EDGES + gwave]; }
    else { s = gwave - N_EDGES; d = s; }
    float alpha = ex_arr[gwave] / fmaxf(denom[d], 1e-16f);
    const float* hs = h + (long)s * CH;
    float* od = out + (long)d * CH;
#pragma unroll
    for (int c = lane; c < CH; c += 64) {
        atomicAdd(&od[c], alpha * hs[c]);
    }
}

// ---- out = selu(out + b) ---------------------------------------------------
__global__ __launch_bounds__(256) void bias_selu(
        float* __restrict__ h, const float* __restrict__ b, long total) {
    long i = (long)blockIdx.x * blockDim.x + threadIdx.x;
    if (i >= total) return;
    float v = h[i] + b[i & (CH - 1)];
    h[i] = selu_f(v);
}

// ---- pool: psum[batch[i]] += h[i]; pcnt[batch[i]] += 1 ---------------------
__global__ __launch_bounds__(256) void pool_sum_kernel(
        const float* __restrict__ h, const int* __restrict__ batch,
        float* __restrict__ psum, float* __restrict__ pcnt, int n) {
    int wave = (blockIdx.x * blockDim.x + threadIdx.x) >> 6;
    int lane = threadIdx.x & 63;
    if (wave >= n) return;
    int g = batch[wave];
    const float* hr = h + (long)wave * CH;
    float* pr = psum + (long)g * CH;
#pragma unroll
    for (int c = lane; c < CH; c += 64) atomicAdd(&pr[c], hr[c]);
    if (lane == 0) atomicAdd(&pcnt[g], 1.f);
}

__global__ __launch_bounds__(256) void pool_finish(
        const float* __restrict__ psum, const float* __restrict__ pcnt,
        float* __restrict__ g1) {
    int i = blockIdx.x * blockDim.x + threadIdx.x;
    if (i >= N_GRAPHS * CH) return;
    int g = i >> 8;
    g1[i] = selu_f(psum[i] / fmaxf(pcnt[g], 1.f));
}

// ---- head: selu(g1 @ fc1 + b1) @ fc2 + b2 -> log_softmax -------------------
__global__ __launch_bounds__(128) void head_kernel(
        const float* __restrict__ g1, const float* __restrict__ fc1W,
        const float* __restrict__ fc1b, const float* __restrict__ fc2W,
        const float* __restrict__ fc2b, float* __restrict__ out) {
    __shared__ float row[CH];
    __shared__ float hrow[HID];
    __shared__ float logits[2];
    int g = blockIdx.x, t = threadIdx.x;
    row[t] = g1[g * CH + t];
    row[t + 128] = g1[g * CH + t + 128];
    __syncthreads();
    float acc = fc1b[t];
    for (int k = 0; k < CH; k++) acc += row[k] * fc1W[k * HID + t];
    hrow[t] = selu_f(acc);
    __syncthreads();
    if (t < 2) {
        float a = fc2b[t];
        for (int k = 0; k < HID; k++) a += hrow[k] * fc2W[k * 2 + t];
        logits[t] = a;
    }
    __syncthreads();
    if (t < 2) {
        float m = fmaxf(logits[0], logits[1]);
        float lse = logf(expf(logits[0] - m) + expf(logits[1] - m)) + m;
        out[g * 2 + t] = logits[t] - lse;
    }
}

extern "C" void kernel_launch(void* const* d_in, const int* in_sizes, int n_in,
                              void* d_out, int out_size, void* d_ws, size_t ws_size,
                              hipStream_t stream) {
    const float* x      = (const float*)d_in[0];
    const int*   ei     = (const int*)d_in[1];
    const int*   batch  = (const int*)d_in[2];
    const float* W1     = (const float*)d_in[3];
    const float* att_l1 = (const float*)d_in[4];
    const float* att_r1 = (const float*)d_in[5];
    const float* b1     = (const float*)d_in[6];
    const float* W2     = (const float*)d_in[7];
    const float* att_l2 = (const float*)d_in[8];
    const float* att_r2 = (const float*)d_in[9];
    const float* b2     = (const float*)d_in[10];
    const float* fc1W   = (const float*)d_in[11];
    const float* fc1b   = (const float*)d_in[12];
    const float* fc2W   = (const float*)d_in[13];
    const float* fc2b   = (const float*)d_in[14];
    float* out = (float*)d_out;

    char* ws = (char*)d_ws;
    size_t off = 0;
    auto alloc = [&](size_t bytes) {
        void* p = ws + off;
        off += (bytes + 255) & ~(size_t)255;
        return p;
    };
    float*    hbuf1  = (float*)alloc((size_t)N_NODES * CH * 4);
    float*    hbuf2  = (float*)alloc((size_t)N_NODES * CH * 4);
    float*    a_src  = (float*)alloc((size_t)N_NODES * 4);
    float*    a_dst  = (float*)alloc((size_t)N_NODES * 4);
    unsigned* m_enc  = (unsigned*)alloc((size_t)N_NODES * 4);
    float*    denom  = (float*)alloc((size_t)N_NODES * 4);
    float*    e_arr  = (float*)alloc((size_t)(N_EDGES + N_NODES) * 4);
    float*    psum   = (float*)alloc((size_t)N_GRAPHS * CH * 4);
    float*    pcnt   = (float*)alloc((size_t)N_GRAPHS * 4);
    float*    g1     = (float*)alloc((size_t)N_GRAPHS * CH * 4);

    const int ET = N_EDGES + N_NODES;
    dim3 blk(256);
    dim3 gemm_grid(CH / BN, (N_NODES + BM - 1) / BM);
    int att_grid  = (N_NODES * 64 + 255) / 256;
    int edge_grid = (ET + 255) / 256;
    int agg_grid  = (int)(((long)ET * 64 + 255) / 256);
    long tot = (long)N_NODES * CH;
    int bs_grid = (int)((tot + 255) / 256);

    // ---------------- Layer 1 ----------------
    gemm_f32<<<gemm_grid, blk, 0, stream>>>(x, W1, hbuf1, N_NODES, CH, F_IN);
    att_kernel<<<att_grid, blk, 0, stream>>>(hbuf1, att_l1, att_r1, a_src, a_dst, N_NODES);
    hipMemsetAsync(m_enc, 0, (size_t)N_NODES * 4, stream);
    hipMemsetAsync(denom, 0, (size_t)N_NODES * 4, stream);
    edge_e_max<<<edge_grid, blk, 0, stream>>>(ei, a_src, a_dst, e_arr, m_enc);
    edge_exp_sum<<<edge_grid, blk, 0, stream>>>(ei, e_arr, m_enc, denom);
    hipMemsetAsync(hbuf2, 0, (size_t)N_NODES * CH * 4, stream);
    edge_aggregate<<<agg_grid, blk, 0, stream>>>(ei, e_arr, denom, hbuf1, hbuf2);
    bias_selu<<<bs_grid, blk, 0, stream>>>(hbuf2, b1, tot);

    // ---------------- Layer 2 ----------------
    gemm_f32<<<gemm_grid, blk, 0, stream>>>(hbuf2, W2, hbuf1, N_NODES, CH, CH);
    att_kernel<<<att_grid, blk, 0, stream>>>(hbuf1, att_l2, att_r2, a_src, a_dst, N_NODES);
    hipMemsetAsync(m_enc, 0, (size_t)N_NODES * 4, stream);
    hipMemsetAsync(denom, 0, (size_t)N_NODES * 4, stream);
    edge_e_max<<<edge_grid, blk, 0, stream>>>(ei, a_src, a_dst, e_arr, m_enc);
    edge_exp_sum<<<edge_grid, blk, 0, stream>>>(ei, e_arr, m_enc, denom);
    hipMemsetAsync(hbuf2, 0, (size_t)N_NODES * CH * 4, stream);
    edge_aggregate<<<agg_grid, blk, 0, stream>>>(ei, e_arr, denom, hbuf1, hbuf2);
    bias_selu<<<bs_grid, blk, 0, stream>>>(hbuf2, b2, tot);

    // ---------------- Pool + head ----------------
    hipMemsetAsync(psum, 0, (size_t)N_GRAPHS * CH * 4, stream);
    hipMemsetAsync(pcnt, 0, (size_t)N_GRAPHS * 4, stream);
    pool_sum_kernel<<<att_grid, blk, 0, stream>>>(hbuf2, batch, psum, pcnt, N_NODES);
    pool_finish<<<(N_GRAPHS * CH + 255) / 256, blk, 0, stream>>>(psum, pcnt, g1);
    head_kernel<<<N_GRAPHS, dim3(128), 0, stream>>>(g1, fc1W, fc1b, fc2W, fc2b, out);
}

// Round 2
// 871.692 us; speedup vs baseline: 2.5882x; 2.5882x over previous
//
#include <hip/hip_runtime.h>
#include <hip/hip_bf16.h>

#define N_NODES 50000
#define N_EDGES 800000
#define N_TOT   (N_EDGES + N_NODES)
#define N_GRAPHS 256
#define F_IN 310
#define CH 256
#define HID 128

__device__ __forceinline__ float selu_f(float x) {
    const float scale = 1.0507009873554805f;
    const float alpha = 1.6732632423543772f;
    return x > 0.f ? scale * x : scale * alpha * (expm1f(x));
}

// ---------------- GEMM: C[M,N] = A[M,K] @ B[K,N], fp32, tiled ----------------
#define BM 128
#define BN 128
#define BKK 8
#define TM 8
#define TN 8
__global__ __launch_bounds__(256) void gemm_f32(
        const float* __restrict__ A, const float* __restrict__ B,
        float* __restrict__ C, int M, int N, int K) {
    __shared__ float As[BKK][BM + 4];
    __shared__ float Bs[BKK][BN + 4];
    int tid = threadIdx.x;
    int col0 = blockIdx.x * BN;
    int row0 = blockIdx.y * BM;
    int tx = tid & 15, ty = tid >> 4;
    float acc[TM][TN] = {};
    int a_r = tid >> 3;   // 0..31
    int a_k = tid & 7;    // 0..7
    int b_k = tid >> 7;   // 0..1
    int b_c = tid & 127;  // 0..127
    for (int k0 = 0; k0 < K; k0 += BKK) {
#pragma unroll
        for (int i = 0; i < 4; i++) {
            int r = a_r + i * 32;
            int gr = row0 + r, gk = k0 + a_k;
            As[a_k][r] = (gr < M && gk < K) ? A[(long)gr * K + gk] : 0.f;
        }
#pragma unroll
        for (int i = 0; i < 4; i++) {
            int k = b_k + i * 2;
            int gk = k0 + k;
            Bs[k][b_c] = (gk < K) ? B[(long)gk * N + col0 + b_c] : 0.f;
        }
        __syncthreads();
#pragma unroll
        for (int kk = 0; kk < BKK; kk++) {
            float af[TM], bf[TN];
#pragma unroll
            for (int i = 0; i < TM; i++) af[i] = As[kk][ty * TM + i];
#pragma unroll
            for (int j = 0; j < TN; j++) bf[j] = Bs[kk][tx * TN + j];
#pragma unroll
            for (int i = 0; i < TM; i++)
#pragma unroll
                for (int j = 0; j < TN; j++) acc[i][j] += af[i] * bf[j];
        }
        __syncthreads();
    }
#pragma unroll
    for (int i = 0; i < TM; i++) {
        int gr = row0 + ty * TM + i;
        if (gr >= M) continue;
#pragma unroll
        for (int j = 0; j < TN; j++) {
            C[(long)gr * N + col0 + tx * TN + j] = acc[i][j];
        }
    }
}

// --------- per-node attention scalars: a_src = h.att_l, a_dst = h.att_r -----
__global__ __launch_bounds__(256) void att_kernel(
        const float* __restrict__ h, const float* __restrict__ att_l,
        const float* __restrict__ att_r, float* __restrict__ a_src,
        float* __restrict__ a_dst, int n) {
    int wave = (blockIdx.x * blockDim.x + threadIdx.x) >> 6;
    int lane = threadIdx.x & 63;
    if (wave >= n) return;
    float sl = 0.f, sr = 0.f;
#pragma unroll
    for (int c = lane; c < CH; c += 64) {
        float v = h[(long)wave * CH + c];
        sl += v * att_l[c];
        sr += v * att_r[c];
    }
#pragma unroll
    for (int off = 32; off > 0; off >>= 1) {
        sl += __shfl_down(sl, off);
        sr += __shfl_down(sr, off);
    }
    if (lane == 0) { a_src[wave] = sl; a_dst[wave] = sr; }
}

// ---------------- CSR build: deg count -> range reserve -> fill -------------
__global__ __launch_bounds__(256) void deg_count(
        const int* __restrict__ ei, int* __restrict__ deg) {
    int eid = blockIdx.x * blockDim.x + threadIdx.x;
    if (eid >= N_TOT) return;
    int d = (eid < N_EDGES) ? ei[N_EDGES + eid] : eid - N_EDGES;
    atomicAdd(&deg[d], 1);
}

__global__ __launch_bounds__(256) void reserve_k(
        const int* __restrict__ deg, int* __restrict__ start,
        int* __restrict__ fillpos, int* __restrict__ cursor, int n) {
    int i = blockIdx.x * blockDim.x + threadIdx.x;
    if (i >= n) return;
    int s = atomicAdd(cursor, deg[i]);
    start[i] = s;
    fillpos[i] = s;
}

__global__ __launch_bounds__(256) void csr_fill(
        const int* __restrict__ ei, int* __restrict__ fillpos,
        int* __restrict__ csr_src) {
    int eid = blockIdx.x * blockDim.x + threadIdx.x;
    if (eid >= N_TOT) return;
    int s, d;
    if (eid < N_EDGES) { s = ei[eid]; d = ei[N_EDGES + eid]; }
    else { s = eid - N_EDGES; d = s; }
    int p = atomicAdd(&fillpos[d], 1);
    csr_src[p] = s;
}

// ---- fused per-dst: softmax over incoming edges + gather-accumulate --------
// one wave per destination node; fuses bias + selu epilogue
__global__ __launch_bounds__(256) void gat_aggregate(
        const int* __restrict__ start, const int* __restrict__ deg,
        const int* __restrict__ csr_src,
        const float* __restrict__ a_src, const float* __restrict__ a_dst,
        const float* __restrict__ h, const float* __restrict__ bias,
        float* __restrict__ out, int n) {
    int node = (blockIdx.x * blockDim.x + threadIdx.x) >> 6;
    int lane = threadIdx.x & 63;
    if (node >= n) return;
    int s0 = start[node];
    int dg = deg[node];
    float ad = a_dst[node];

    // pass 1: segment max (lane-strided over edges)
    float m = -1e30f;
    for (int i = lane; i < dg; i += 64) {
        int s = csr_src[s0 + i];
        float e = a_src[s] + ad;
        e = e > 0.f ? e : 0.2f * e;
        m = fmaxf(m, e);
    }
#pragma unroll
    for (int off = 32; off > 0; off >>= 1) m = fmaxf(m, __shfl_xor(m, off));

    // pass 2: softmax denom
    float sum = 0.f;
    for (int i = lane; i < dg; i += 64) {
        int s = csr_src[s0 + i];
        float e = a_src[s] + ad;
        e = e > 0.f ? e : 0.2f * e;
        sum += __expf(e - m);
    }
#pragma unroll
    for (int off = 32; off > 0; off >>= 1) sum += __shfl_xor(sum, off);
    float inv = 1.f / fmaxf(sum, 1e-16f);

    // pass 3: weighted gather-accumulate; lanes own 4 contiguous channels
    float4 acc = {0.f, 0.f, 0.f, 0.f};
    for (int i = 0; i < dg; i++) {
        int s = csr_src[s0 + i];                 // broadcast
        float e = a_src[s] + ad;                 // broadcast
        e = e > 0.f ? e : 0.2f * e;
        float alpha = __expf(e - m) * inv;
        float4 hv = *(const float4*)(h + (long)s * CH + lane * 4);
        acc.x += alpha * hv.x;
        acc.y += alpha * hv.y;
        acc.z += alpha * hv.z;
        acc.w += alpha * hv.w;
    }
    float4 bv = *(const float4*)(bias + lane * 4);
    float4 o;
    o.x = selu_f(acc.x + bv.x);
    o.y = selu_f(acc.y + bv.y);
    o.z = selu_f(acc.z + bv.z);
    o.w = selu_f(acc.w + bv.w);
    *(float4*)(out + (long)node * CH + lane * 4) = o;
}

// ---- pool: batch is SORTED -> per-graph segment via binary search ----------
__global__ __launch_bounds__(256) void pool_kernel(
        const float* __restrict__ h, const int* __restrict__ batch,
        float* __restrict__ g1) {
    int g = blockIdx.x;
    int t = threadIdx.x;
    int lo, hi;
    { int a = 0, b = N_NODES;
      while (a < b) { int mid = (a + b) >> 1; if (batch[mid] < g) a = mid + 1; else b = mid; }
      lo = a; }
    { int a = lo, b = N_NODES;
      while (a < b) { int mid = (a + b) >> 1; if (batch[mid] < g + 1) a = mid + 1; else b = mid; }
      hi = a; }
    float acc = 0.f;
    for (int i = lo; i < hi; i++) acc += h[(long)i * CH + t];
    float cnt = (float)(hi - lo);
    g1[g * CH + t] = selu_f(acc / fmaxf(cnt, 1.f));
}

// ---- head: selu(g1 @ fc1 + b1) @ fc2 + b2 -> log_softmax -------------------
__global__ __launch_bounds__(128) void head_kernel(
        const float* __restrict__ g1, const float* __restrict__ fc1W,
        const float* __restrict__ fc1b, const float* __restrict__ fc2W,
        const float* __restrict__ fc2b, float* __restrict__ out) {
    __shared__ float row[CH];
    __shared__ float hrow[HID];
    __shared__ float logits[2];
    int g = blockIdx.x, t = threadIdx.x;
    row[t] = g1[g * CH + t];
    row[t + 128] = g1[g * CH + t + 128];
    __syncthreads();
    float acc = fc1b[t];
    for (int k = 0; k < CH; k++) acc += row[k] * fc1W[k * HID + t];
    hrow[t] = selu_f(acc);
    __syncthreads();
    if (t < 2) {
        float a = fc2b[t];
        for (int k = 0; k < HID; k++) a += hrow[k] * fc2W[k * 2 + t];
        logits[t] = a;
    }
    __syncthreads();
    if (t < 2) {
        float m = fmaxf(logits[0], logits[1]);
        float lse = logf(expf(logits[0] - m) + expf(logits[1] - m)) + m;
        out[g * 2 + t] = logits[t] - lse;
    }
}

extern "C" void kernel_launch(void* const* d_in, const int* in_sizes, int n_in,
                              void* d_out, int out_size, void* d_ws, size_t ws_size,
                              hipStream_t stream) {
    const float* x      = (const float*)d_in[0];
    const int*   ei     = (const int*)d_in[1];
    const int*   batch  = (const int*)d_in[2];
    const float* W1     = (const float*)d_in[3];
    const float* att_l1 = (const float*)d_in[4];
    const float* att_r1 = (const float*)d_in[5];
    const float* b1     = (const float*)d_in[6];
    const float* W2     = (const float*)d_in[7];
    const float* att_l2 = (const float*)d_in[8];
    const float* att_r2 = (const float*)d_in[9];
    const float* b2     = (const float*)d_in[10];
    const float* fc1W   = (const float*)d_in[11];
    const float* fc1b   = (const float*)d_in[12];
    const float* fc2W   = (const float*)d_in[13];
    const float* fc2b   = (const float*)d_in[14];
    float* out = (float*)d_out;

    char* ws = (char*)d_ws;
    size_t off = 0;
    auto alloc = [&](size_t bytes) {
        void* p = ws + off;
        off += (bytes + 255) & ~(size_t)255;
        return p;
    };
    float* hbuf1   = (float*)alloc((size_t)N_NODES * CH * 4);
    float* hbuf2   = (float*)alloc((size_t)N_NODES * CH * 4);
    float* a_src   = (float*)alloc((size_t)N_NODES * 4);
    float* a_dst   = (float*)alloc((size_t)N_NODES * 4);
    int*   deg     = (int*)alloc((size_t)N_NODES * 4);
    int*   startA  = (int*)alloc((size_t)N_NODES * 4);
    int*   fillpos = (int*)alloc((size_t)N_NODES * 4);
    int*   csr_src = (int*)alloc((size_t)N_TOT * 4);
    int*   cursor  = (int*)alloc(256);
    float* g1      = (float*)alloc((size_t)N_GRAPHS * CH * 4);

    dim3 blk(256);
    dim3 gemm_grid(CH / BN, (N_NODES + BM - 1) / BM);
    int att_grid  = (N_NODES * 64 + 255) / 256;
    int edge_grid = (N_TOT + 255) / 256;
    int node_grid = (N_NODES + 255) / 256;
    int agg_grid  = (int)(((long)N_NODES * 64 + 255) / 256);

    // ---------------- CSR build (shared by both layers) ----------------
    hipMemsetAsync(deg, 0, (size_t)N_NODES * 4, stream);
    hipMemsetAsync(cursor, 0, 4, stream);
    deg_count<<<edge_grid, blk, 0, stream>>>(ei, deg);
    reserve_k<<<node_grid, blk, 0, stream>>>(deg, startA, fillpos, cursor, N_NODES);
    csr_fill<<<edge_grid, blk, 0, stream>>>(ei, fillpos, csr_src);

    // ---------------- Layer 1 ----------------
    gemm_f32<<<gemm_grid, blk, 0, stream>>>(x, W1, hbuf1, N_NODES, CH, F_IN);
    att_kernel<<<att_grid, blk, 0, stream>>>(hbuf1, att_l1, att_r1, a_src, a_dst, N_NODES);
    gat_aggregate<<<agg_grid, blk, 0, stream>>>(startA, deg, csr_src, a_src, a_dst,
                                                hbuf1, b1, hbuf2, N_NODES);

    // ---------------- Layer 2 ----------------
    gemm_f32<<<gemm_grid, blk, 0, stream>>>(hbuf2, W2, hbuf1, N_NODES, CH, CH);
    att_kernel<<<att_grid, blk, 0, stream>>>(hbuf1, att_l2, att_r2, a_src, a_dst, N_NODES);
    gat_aggregate<<<agg_grid, blk, 0, stream>>>(startA, deg, csr_src, a_src, a_dst,
                                                hbuf1, b2, hbuf2, N_NODES);

    // ---------------- Pool + head ----------------
    pool_kernel<<<N_GRAPHS, blk, 0, stream>>>(hbuf2, batch, g1);
    head_kernel<<<N_GRAPHS, dim3(128), 0, stream>>>(g1, fc1W, fc1b, fc2W, fc2b, out);
}

// Round 3
// 529.205 us; speedup vs baseline: 4.2633x; 1.6472x over previous
//
#include <hip/hip_runtime.h>
#include <hip/hip_bf16.h>

#define N_NODES 50000
#define N_EDGES 800000
#define N_TOT   (N_EDGES + N_NODES)
#define N_GRAPHS 256
#define F_IN 310
#define KP1 320          // F_IN padded to multiple of 32
#define CH 256
#define HID 128

typedef __attribute__((ext_vector_type(8))) short short8;
typedef __attribute__((ext_vector_type(4))) float f32x4;
typedef unsigned short ushort_t;

__device__ __forceinline__ float selu_f(float x) {
    const float scale = 1.0507009873554805f;
    const float alpha = 1.6732632423543772f;
    return x > 0.f ? scale * x : scale * alpha * (expm1f(x));
}

__device__ __forceinline__ ushort_t f32_to_bf16_rne(float f) {
    unsigned u = __float_as_uint(f);
    unsigned rounding = 0x7FFFu + ((u >> 16) & 1u);
    return (ushort_t)((u + rounding) >> 16);
}

// ---- convert x [N, 310] f32 -> A [N, 320] bf16 (zero-padded) ---------------
__global__ __launch_bounds__(256) void convert_pad_x(
        const float* __restrict__ x, ushort_t* __restrict__ A) {
    long i = (long)blockIdx.x * blockDim.x + threadIdx.x;
    if (i >= (long)N_NODES * KP1) return;
    int r = (int)(i / KP1), c = (int)(i % KP1);
    A[i] = (c < F_IN) ? f32_to_bf16_rne(x[(long)r * F_IN + c]) : 0;
}

// ---- W [K, 256] f32 -> Wt [256, Kp] bf16 (transposed, zero-padded) ---------
__global__ __launch_bounds__(256) void convert_wt(
        const float* __restrict__ W, ushort_t* __restrict__ Wt, int K, int Kp) {
    int i = blockIdx.x * blockDim.x + threadIdx.x;
    if (i >= CH * Kp) return;
    int n = i / Kp, k = i % Kp;
    Wt[i] = (k < K) ? f32_to_bf16_rne(W[(long)k * CH + n]) : 0;
}

// ---------------- MFMA GEMM: C[M,256] = A[M,Kp]bf16 @ Wt[256,Kp]^T ----------
// block = 256 thr (4 waves), tile 128x128, K-step 32.
// LDS tiles stored as [outer(128)][32] bf16, 16B chunks XOR-swizzled: c' = c ^ (r&3)
__global__ __launch_bounds__(256) void gemm_bf16(
        const ushort_t* __restrict__ A, const ushort_t* __restrict__ Bt,
        float* __restrict__ C, int M, int Kp) {
    __shared__ __align__(16) ushort_t As[128 * 32];
    __shared__ __align__(16) ushort_t Bs[128 * 32];
    int tid = threadIdx.x;
    int col0 = blockIdx.x * 128;
    int row0 = blockIdx.y * 128;
    int w = tid >> 6, l = tid & 63;
    int lr = l & 15, lc = l >> 4;       // fragment: row-within-16, k-chunk
    f32x4 acc[2][8] = {};
    int sr = tid >> 2;                  // staging row 0..63
    int sc = tid & 3;                   // staging 16B chunk 0..3

    for (int k0 = 0; k0 < Kp; k0 += 32) {
#pragma unroll
        for (int i = 0; i < 2; i++) {
            int r = sr + i * 64;
            int grow = row0 + r;
            int4 av = {0, 0, 0, 0};
            if (grow < M) av = *(const int4*)(A + (size_t)grow * Kp + k0 + sc * 8);
            *(int4*)(As + r * 32 + ((sc ^ (r & 3)) * 8)) = av;
            int4 bv = *(const int4*)(Bt + (size_t)(col0 + r) * Kp + k0 + sc * 8);
            *(int4*)(Bs + r * 32 + ((sc ^ (r & 3)) * 8)) = bv;
        }
        __syncthreads();
        short8 af[2], bf[8];
#pragma unroll
        for (int mi = 0; mi < 2; mi++) {
            int r = w * 32 + mi * 16 + lr;
            af[mi] = *(const short8*)(As + r * 32 + ((lc ^ (r & 3)) * 8));
        }
#pragma unroll
        for (int ni = 0; ni < 8; ni++) {
            int r = ni * 16 + lr;
            bf[ni] = *(const short8*)(Bs + r * 32 + ((lc ^ (r & 3)) * 8));
        }
#pragma unroll
        for (int mi = 0; mi < 2; mi++)
#pragma unroll
            for (int ni = 0; ni < 8; ni++)
                acc[mi][ni] = __builtin_amdgcn_mfma_f32_16x16x32_bf16(
                    af[mi], bf[ni], acc[mi][ni], 0, 0, 0);
        __syncthreads();
    }
    // C/D layout: col = lane&15, row = (lane>>4)*4 + q
#pragma unroll
    for (int mi = 0; mi < 2; mi++) {
        int rbase = row0 + w * 32 + mi * 16 + lc * 4;
#pragma unroll
        for (int ni = 0; ni < 8; ni++) {
            int col = col0 + ni * 16 + lr;
#pragma unroll
            for (int q = 0; q < 4; q++) {
                int grow = rbase + q;
                if (grow < M) C[(size_t)grow * CH + col] = acc[mi][ni][q];
            }
        }
    }
}

// --------- per-node attention scalars: a_src = h.att_l, a_dst = h.att_r -----
__global__ __launch_bounds__(256) void att_kernel(
        const float* __restrict__ h, const float* __restrict__ att_l,
        const float* __restrict__ att_r, float* __restrict__ a_src,
        float* __restrict__ a_dst, int n) {
    int wave = (blockIdx.x * blockDim.x + threadIdx.x) >> 6;
    int lane = threadIdx.x & 63;
    if (wave >= n) return;
    float sl = 0.f, sr = 0.f;
#pragma unroll
    for (int c = lane; c < CH; c += 64) {
        float v = h[(long)wave * CH + c];
        sl += v * att_l[c];
        sr += v * att_r[c];
    }
#pragma unroll
    for (int off = 32; off > 0; off >>= 1) {
        sl += __shfl_down(sl, off);
        sr += __shfl_down(sr, off);
    }
    if (lane == 0) { a_src[wave] = sl; a_dst[wave] = sr; }
}

// ---------------- CSR build: deg count -> range reserve -> fill -------------
__global__ __launch_bounds__(256) void deg_count(
        const int* __restrict__ ei, int* __restrict__ deg) {
    int eid = blockIdx.x * blockDim.x + threadIdx.x;
    if (eid >= N_TOT) return;
    int d = (eid < N_EDGES) ? ei[N_EDGES + eid] : eid - N_EDGES;
    atomicAdd(&deg[d], 1);
}

__global__ __launch_bounds__(256) void reserve_k(
        const int* __restrict__ deg, int* __restrict__ start,
        int* __restrict__ fillpos, int* __restrict__ cursor, int n) {
    int i = blockIdx.x * blockDim.x + threadIdx.x;
    if (i >= n) return;
    int s = atomicAdd(cursor, deg[i]);
    start[i] = s;
    fillpos[i] = s;
}

__global__ __launch_bounds__(256) void csr_fill(
        const int* __restrict__ ei, int* __restrict__ fillpos,
        int* __restrict__ csr_src) {
    int eid = blockIdx.x * blockDim.x + threadIdx.x;
    if (eid >= N_TOT) return;
    int s, d;
    if (eid < N_EDGES) { s = ei[eid]; d = ei[N_EDGES + eid]; }
    else { s = eid - N_EDGES; d = s; }
    int p = atomicAdd(&fillpos[d], 1);
    csr_src[p] = s;
}

// ---- fused per-dst: softmax over incoming edges + gather-accumulate --------
// one wave per destination node; fuses bias + selu; optional bf16 copy out
__global__ __launch_bounds__(256) void gat_aggregate(
        const int* __restrict__ start, const int* __restrict__ deg,
        const int* __restrict__ csr_src,
        const float* __restrict__ a_src, const float* __restrict__ a_dst,
        const float* __restrict__ h, const float* __restrict__ bias,
        float* __restrict__ out, ushort_t* __restrict__ out_bf, int n) {
    int node = (blockIdx.x * blockDim.x + threadIdx.x) >> 6;
    int lane = threadIdx.x & 63;
    if (node >= n) return;
    int s0 = start[node];
    int dg = deg[node];
    float ad = a_dst[node];

    float m = -1e30f;
    for (int i = lane; i < dg; i += 64) {
        int s = csr_src[s0 + i];
        float e = a_src[s] + ad;
        e = e > 0.f ? e : 0.2f * e;
        m = fmaxf(m, e);
    }
#pragma unroll
    for (int off = 32; off > 0; off >>= 1) m = fmaxf(m, __shfl_xor(m, off));

    float sum = 0.f;
    for (int i = lane; i < dg; i += 64) {
        int s = csr_src[s0 + i];
        float e = a_src[s] + ad;
        e = e > 0.f ? e : 0.2f * e;
        sum += __expf(e - m);
    }
#pragma unroll
    for (int off = 32; off > 0; off >>= 1) sum += __shfl_xor(sum, off);
    float inv = 1.f / fmaxf(sum, 1e-16f);

    float4 acc = {0.f, 0.f, 0.f, 0.f};
    for (int i = 0; i < dg; i++) {
        int s = csr_src[s0 + i];
        float e = a_src[s] + ad;
        e = e > 0.f ? e : 0.2f * e;
        float alpha = __expf(e - m) * inv;
        float4 hv = *(const float4*)(h + (long)s * CH + lane * 4);
        acc.x += alpha * hv.x;
        acc.y += alpha * hv.y;
        acc.z += alpha * hv.z;
        acc.w += alpha * hv.w;
    }
    float4 bv = *(const float4*)(bias + lane * 4);
    float4 o;
    o.x = selu_f(acc.x + bv.x);
    o.y = selu_f(acc.y + bv.y);
    o.z = selu_f(acc.z + bv.z);
    o.w = selu_f(acc.w + bv.w);
    *(float4*)(out + (long)node * CH + lane * 4) = o;
    if (out_bf) {
        ushort4 ob;
        ob.x = f32_to_bf16_rne(o.x);
        ob.y = f32_to_bf16_rne(o.y);
        ob.z = f32_to_bf16_rne(o.z);
        ob.w = f32_to_bf16_rne(o.w);
        *(ushort4*)(out_bf + (long)node * CH + lane * 4) = ob;
    }
}

// ---- pool: batch is SORTED -> per-graph segment via binary search ----------
__global__ __launch_bounds__(256) void pool_kernel(
        const float* __restrict__ h, const int* __restrict__ batch,
        float* __restrict__ g1) {
    int g = blockIdx.x;
    int t = threadIdx.x;
    int lo, hi;
    { int a = 0, b = N_NODES;
      while (a < b) { int mid = (a + b) >> 1; if (batch[mid] < g) a = mid + 1; else b = mid; }
      lo = a; }
    { int a = lo, b = N_NODES;
      while (a < b) { int mid = (a + b) >> 1; if (batch[mid] < g + 1) a = mid + 1; else b = mid; }
      hi = a; }
    float acc = 0.f;
    for (int i = lo; i < hi; i++) acc += h[(long)i * CH + t];
    float cnt = (float)(hi - lo);
    g1[g * CH + t] = selu_f(acc / fmaxf(cnt, 1.f));
}

// ---- head: selu(g1 @ fc1 + b1) @ fc2 + b2 -> log_softmax -------------------
__global__ __launch_bounds__(128) void head_kernel(
        const float* __restrict__ g1, const float* __restrict__ fc1W,
        const float* __restrict__ fc1b, const float* __restrict__ fc2W,
        const float* __restrict__ fc2b, float* __restrict__ out) {
    __shared__ float row[CH];
    __shared__ float hrow[HID];
    __shared__ float logits[2];
    int g = blockIdx.x, t = threadIdx.x;
    row[t] = g1[g * CH + t];
    row[t + 128] = g1[g * CH + t + 128];
    __syncthreads();
    float acc = fc1b[t];
    for (int k = 0; k < CH; k++) acc += row[k] * fc1W[k * HID + t];
    hrow[t] = selu_f(acc);
    __syncthreads();
    if (t < 2) {
        float a = fc2b[t];
        for (int k = 0; k < HID; k++) a += hrow[k] * fc2W[k * 2 + t];
        logits[t] = a;
    }
    __syncthreads();
    if (t < 2) {
        float m = fmaxf(logits[0], logits[1]);
        float lse = logf(expf(logits[0] - m) + expf(logits[1] - m)) + m;
        out[g * 2 + t] = logits[t] - lse;
    }
}

extern "C" void kernel_launch(void* const* d_in, const int* in_sizes, int n_in,
                              void* d_out, int out_size, void* d_ws, size_t ws_size,
                              hipStream_t stream) {
    const float* x      = (const float*)d_in[0];
    const int*   ei     = (const int*)d_in[1];
    const int*   batch  = (const int*)d_in[2];
    const float* W1     = (const float*)d_in[3];
    const float* att_l1 = (const float*)d_in[4];
    const float* att_r1 = (const float*)d_in[5];
    const float* b1     = (const float*)d_in[6];
    const float* W2     = (const float*)d_in[7];
    const float* att_l2 = (const float*)d_in[8];
    const float* att_r2 = (const float*)d_in[9];
    const float* b2     = (const float*)d_in[10];
    const float* fc1W   = (const float*)d_in[11];
    const float* fc1b   = (const float*)d_in[12];
    const float* fc2W   = (const float*)d_in[13];
    const float* fc2b   = (const float*)d_in[14];
    float* out = (float*)d_out;

    char* ws = (char*)d_ws;
    size_t off = 0;
    auto alloc = [&](size_t bytes) {
        void* p = ws + off;
        off += (bytes + 255) & ~(size_t)255;
        return p;
    };
    float*    hbuf1  = (float*)alloc((size_t)N_NODES * CH * 4);
    float*    hbuf2  = (float*)alloc((size_t)N_NODES * CH * 4);
    ushort_t* Ab     = (ushort_t*)alloc((size_t)N_NODES * KP1 * 2);   // x bf16 padded
    ushort_t* Zb     = (ushort_t*)alloc((size_t)N_NODES * CH * 2);    // z1 bf16
    ushort_t* W1t    = (ushort_t*)alloc((size_t)CH * KP1 * 2);
    ushort_t* W2t    = (ushort_t*)alloc((size_t)CH * CH * 2);
    float*    a_src  = (float*)alloc((size_t)N_NODES * 4);
    float*    a_dst  = (float*)alloc((size_t)N_NODES * 4);
    int*      deg    = (int*)alloc((size_t)N_NODES * 4);
    int*      startA = (int*)alloc((size_t)N_NODES * 4);
    int*      fillpos= (int*)alloc((size_t)N_NODES * 4);
    int*      csr_src= (int*)alloc((size_t)N_TOT * 4);
    int*      cursor = (int*)alloc(256);
    float*    g1     = (float*)alloc((size_t)N_GRAPHS * CH * 4);

    dim3 blk(256);
    dim3 gemm_grid(CH / 128, (N_NODES + 127) / 128);
    int att_grid  = (N_NODES * 64 + 255) / 256;
    int edge_grid = (N_TOT + 255) / 256;
    int node_grid = (N_NODES + 255) / 256;
    int agg_grid  = (int)(((long)N_NODES * 64 + 255) / 256);
    long xconv = (long)N_NODES * KP1;

    // ---------------- input conversions + CSR build ----------------
    convert_pad_x<<<(int)((xconv + 255) / 256), blk, 0, stream>>>(x, Ab);
    convert_wt<<<(CH * KP1 + 255) / 256, blk, 0, stream>>>(W1, W1t, F_IN, KP1);
    convert_wt<<<(CH * CH + 255) / 256, blk, 0, stream>>>(W2, W2t, CH, CH);
    hipMemsetAsync(deg, 0, (size_t)N_NODES * 4, stream);
    hipMemsetAsync(cursor, 0, 4, stream);
    deg_count<<<edge_grid, blk, 0, stream>>>(ei, deg);
    reserve_k<<<node_grid, blk, 0, stream>>>(deg, startA, fillpos, cursor, N_NODES);
    csr_fill<<<edge_grid, blk, 0, stream>>>(ei, fillpos, csr_src);

    // ---------------- Layer 1 ----------------
    gemm_bf16<<<gemm_grid, blk, 0, stream>>>(Ab, W1t, hbuf1, N_NODES, KP1);
    att_kernel<<<att_grid, blk, 0, stream>>>(hbuf1, att_l1, att_r1, a_src, a_dst, N_NODES);
    gat_aggregate<<<agg_grid, blk, 0, stream>>>(startA, deg, csr_src, a_src, a_dst,
                                                hbuf1, b1, hbuf2, Zb, N_NODES);

    // ---------------- Layer 2 ----------------
    gemm_bf16<<<gemm_grid, blk, 0, stream>>>(Zb, W2t, hbuf1, N_NODES, CH);
    att_kernel<<<att_grid, blk, 0, stream>>>(hbuf1, att_l2, att_r2, a_src, a_dst, N_NODES);
    gat_aggregate<<<agg_grid, blk, 0, stream>>>(startA, deg, csr_src, a_src, a_dst,
                                                hbuf1, b2, hbuf2, (ushort_t*)nullptr, N_NODES);

    // ---------------- Pool + head ----------------
    pool_kernel<<<N_GRAPHS, blk, 0, stream>>>(hbuf2, batch, g1);
    head_kernel<<<N_GRAPHS, dim3(128), 0, stream>>>(g1, fc1W, fc1b, fc2W, fc2b, out);
}

// Round 4
// 493.208 us; speedup vs baseline: 4.5744x; 1.0730x over previous
//
#include <hip/hip_runtime.h>
#include <hip/hip_bf16.h>

#define N_NODES 50000
#define N_EDGES 800000
#define N_TOT   (N_EDGES + N_NODES)
#define N_GRAPHS 256
#define F_IN 310
#define KP1 320          // F_IN padded to multiple of 32
#define CH 256
#define HID 128

typedef __attribute__((ext_vector_type(8))) short short8;
typedef __attribute__((ext_vector_type(4))) float f32x4;
typedef unsigned short ushort_t;

__device__ __forceinline__ float selu_f(float x) {
    const float scale = 1.0507009873554805f;
    const float alpha = 1.6732632423543772f;
    return x > 0.f ? scale * x : scale * alpha * (expm1f(x));
}

__device__ __forceinline__ ushort_t f32_to_bf16_rne(float f) {
    unsigned u = __float_as_uint(f);
    unsigned rounding = 0x7FFFu + ((u >> 16) & 1u);
    return (ushort_t)((u + rounding) >> 16);
}
__device__ __forceinline__ float bf16_to_f32(ushort_t v) {
    return __uint_as_float(((unsigned)v) << 16);
}

// ---- convert x [N, 310] f32 -> A [N, 320] bf16 (zero-padded) ---------------
__global__ __launch_bounds__(256) void convert_pad_x(
        const float* __restrict__ x, ushort_t* __restrict__ A) {
    long i = (long)blockIdx.x * blockDim.x + threadIdx.x;
    if (i >= (long)N_NODES * KP1) return;
    int r = (int)(i / KP1), c = (int)(i % KP1);
    A[i] = (c < F_IN) ? f32_to_bf16_rne(x[(long)r * F_IN + c]) : 0;
}

// ---- W [K, 256] f32 -> Wt [256, Kp] bf16 (transposed, zero-padded) ---------
__global__ __launch_bounds__(256) void convert_wt(
        const float* __restrict__ W, ushort_t* __restrict__ Wt, int K, int Kp) {
    int i = blockIdx.x * blockDim.x + threadIdx.x;
    if (i >= CH * Kp) return;
    int n = i / Kp, k = i % Kp;
    Wt[i] = (k < K) ? f32_to_bf16_rne(W[(long)k * CH + n]) : 0;
}

// ------- MFMA GEMM + fused attention-scalar epilogue ------------------------
// C[M,256] = A[M,Kp]bf16 @ Wt[256,Kp]^T, written as bf16.
// Also: a_src[r] += h[r].att_l, a_dst[r] += h[r].att_r (partial per col-block,
// computed from f32 accumulators, 16-lane reduce, 1 atomic per row/vec).
// block = 256 thr (4 waves), tile 128x128, K-step 32.
// LDS tiles [outer(128)][32] bf16, 16B chunks XOR-swizzled: c' = c ^ (r&3)
__global__ __launch_bounds__(256) void gemm_bf16_fused(
        const ushort_t* __restrict__ A, const ushort_t* __restrict__ Bt,
        ushort_t* __restrict__ Cb, const float* __restrict__ att_l,
        const float* __restrict__ att_r, float* __restrict__ a_src,
        float* __restrict__ a_dst, int M, int Kp) {
    __shared__ __align__(16) ushort_t As[128 * 32];
    __shared__ __align__(16) ushort_t Bs[128 * 32];
    int tid = threadIdx.x;
    int col0 = blockIdx.x * 128;
    int row0 = blockIdx.y * 128;
    int w = tid >> 6, l = tid & 63;
    int lr = l & 15, lc = l >> 4;       // fragment: row-within-16, k-chunk
    f32x4 acc[2][8] = {};
    int sr = tid >> 2;                  // staging row 0..63
    int sc = tid & 3;                   // staging 16B chunk 0..3

    for (int k0 = 0; k0 < Kp; k0 += 32) {
#pragma unroll
        for (int i = 0; i < 2; i++) {
            int r = sr + i * 64;
            int grow = row0 + r;
            int4 av = {0, 0, 0, 0};
            if (grow < M) av = *(const int4*)(A + (size_t)grow * Kp + k0 + sc * 8);
            *(int4*)(As + r * 32 + ((sc ^ (r & 3)) * 8)) = av;
            int4 bv = *(const int4*)(Bt + (size_t)(col0 + r) * Kp + k0 + sc * 8);
            *(int4*)(Bs + r * 32 + ((sc ^ (r & 3)) * 8)) = bv;
        }
        __syncthreads();
        short8 af[2], bf[8];
#pragma unroll
        for (int mi = 0; mi < 2; mi++) {
            int r = w * 32 + mi * 16 + lr;
            af[mi] = *(const short8*)(As + r * 32 + ((lc ^ (r & 3)) * 8));
        }
#pragma unroll
        for (int ni = 0; ni < 8; ni++) {
            int r = ni * 16 + lr;
            bf[ni] = *(const short8*)(Bs + r * 32 + ((lc ^ (r & 3)) * 8));
        }
#pragma unroll
        for (int mi = 0; mi < 2; mi++)
#pragma unroll
            for (int ni = 0; ni < 8; ni++)
                acc[mi][ni] = __builtin_amdgcn_mfma_f32_16x16x32_bf16(
                    af[mi], bf[ni], acc[mi][ni], 0, 0, 0);
        __syncthreads();
    }
    // C/D layout: col = lane&15, row = (lane>>4)*4 + q
    float al[8], ar[8];
#pragma unroll
    for (int ni = 0; ni < 8; ni++) {
        int col = col0 + ni * 16 + lr;
        al[ni] = att_l[col];
        ar[ni] = att_r[col];
    }
#pragma unroll
    for (int mi = 0; mi < 2; mi++) {
        int rbase = row0 + w * 32 + mi * 16 + lc * 4;
#pragma unroll
        for (int q = 0; q < 4; q++) {
            int grow = rbase + q;
            float pl = 0.f, pr = 0.f;
#pragma unroll
            for (int ni = 0; ni < 8; ni++) {
                float v = acc[mi][ni][q];
                pl += v * al[ni];
                pr += v * ar[ni];
                if (grow < M) Cb[(size_t)grow * CH + col0 + ni * 16 + lr] = f32_to_bf16_rne(v);
            }
#pragma unroll
            for (int off = 1; off < 16; off <<= 1) {
                pl += __shfl_xor(pl, off);
                pr += __shfl_xor(pr, off);
            }
            if (lr == 0 && grow < M) {
                atomicAdd(&a_src[grow], pl);
                atomicAdd(&a_dst[grow], pr);
            }
        }
    }
}

// ---------------- CSR build: deg count -> range reserve -> fill -------------
__global__ __launch_bounds__(256) void deg_count(
        const int* __restrict__ ei, int* __restrict__ deg) {
    int eid = blockIdx.x * blockDim.x + threadIdx.x;
    if (eid >= N_TOT) return;
    int d = (eid < N_EDGES) ? ei[N_EDGES + eid] : eid - N_EDGES;
    atomicAdd(&deg[d], 1);
}

__global__ __launch_bounds__(256) void reserve_k(
        const int* __restrict__ deg, int* __restrict__ start,
        int* __restrict__ fillpos, int* __restrict__ cursor, int n) {
    int i = blockIdx.x * blockDim.x + threadIdx.x;
    if (i >= n) return;
    int s = atomicAdd(cursor, deg[i]);
    start[i] = s;
    fillpos[i] = s;
}

__global__ __launch_bounds__(256) void csr_fill(
        const int* __restrict__ ei, int* __restrict__ fillpos,
        int* __restrict__ csr_src) {
    int eid = blockIdx.x * blockDim.x + threadIdx.x;
    if (eid >= N_TOT) return;
    int s, d;
    if (eid < N_EDGES) { s = ei[eid]; d = ei[N_EDGES + eid]; }
    else { s = eid - N_EDGES; d = s; }
    int p = atomicAdd(&fillpos[d], 1);
    csr_src[p] = s;
}

// ---- fused per-dst: softmax over incoming edges + bf16 gather-accumulate ---
// one wave per destination node; fuses bias + selu epilogue.
// h is bf16 [N, 256]; out_f32 / out_bf optional.
__global__ __launch_bounds__(256) void gat_aggregate(
        const int* __restrict__ start, const int* __restrict__ deg,
        const int* __restrict__ csr_src,
        const float* __restrict__ a_src, const float* __restrict__ a_dst,
        const ushort_t* __restrict__ h, const float* __restrict__ bias,
        float* __restrict__ out_f32, ushort_t* __restrict__ out_bf, int n) {
    int node = (blockIdx.x * blockDim.x + threadIdx.x) >> 6;
    int lane = threadIdx.x & 63;
    if (node >= n) return;
    int s0 = start[node];
    int dg = deg[node];
    float ad = a_dst[node];

    float m = -1e30f;
    for (int i = lane; i < dg; i += 64) {
        int s = csr_src[s0 + i];
        float e = a_src[s] + ad;
        e = e > 0.f ? e : 0.2f * e;
        m = fmaxf(m, e);
    }
#pragma unroll
    for (int off = 32; off > 0; off >>= 1) m = fmaxf(m, __shfl_xor(m, off));

    float sum = 0.f;
    for (int i = lane; i < dg; i += 64) {
        int s = csr_src[s0 + i];
        float e = a_src[s] + ad;
        e = e > 0.f ? e : 0.2f * e;
        sum += __expf(e - m);
    }
#pragma unroll
    for (int off = 32; off > 0; off >>= 1) sum += __shfl_xor(sum, off);
    float inv = 1.f / fmaxf(sum, 1e-16f);

    float4 acc = {0.f, 0.f, 0.f, 0.f};
    for (int i = 0; i < dg; i++) {
        int s = csr_src[s0 + i];
        float e = a_src[s] + ad;
        e = e > 0.f ? e : 0.2f * e;
        float alpha = __expf(e - m) * inv;
        ushort4 hv = *(const ushort4*)(h + (long)s * CH + lane * 4);
        acc.x += alpha * bf16_to_f32(hv.x);
        acc.y += alpha * bf16_to_f32(hv.y);
        acc.z += alpha * bf16_to_f32(hv.z);
        acc.w += alpha * bf16_to_f32(hv.w);
    }
    float4 bv = *(const float4*)(bias + lane * 4);
    float4 o;
    o.x = selu_f(acc.x + bv.x);
    o.y = selu_f(acc.y + bv.y);
    o.z = selu_f(acc.z + bv.z);
    o.w = selu_f(acc.w + bv.w);
    if (out_f32) *(float4*)(out_f32 + (long)node * CH + lane * 4) = o;
    if (out_bf) {
        ushort4 ob;
        ob.x = f32_to_bf16_rne(o.x);
        ob.y = f32_to_bf16_rne(o.y);
        ob.z = f32_to_bf16_rne(o.z);
        ob.w = f32_to_bf16_rne(o.w);
        *(ushort4*)(out_bf + (long)node * CH + lane * 4) = ob;
    }
}

// ---- pool: batch is SORTED -> per-graph segment via binary search ----------
__global__ __launch_bounds__(256) void pool_kernel(
        const float* __restrict__ h, const int* __restrict__ batch,
        float* __restrict__ g1) {
    int g = blockIdx.x;
    int t = threadIdx.x;
    int lo, hi;
    { int a = 0, b = N_NODES;
      while (a < b) { int mid = (a + b) >> 1; if (batch[mid] < g) a = mid + 1; else b = mid; }
      lo = a; }
    { int a = lo, b = N_NODES;
      while (a < b) { int mid = (a + b) >> 1; if (batch[mid] < g + 1) a = mid + 1; else b = mid; }
      hi = a; }
    float acc = 0.f;
    for (int i = lo; i < hi; i++) acc += h[(long)i * CH + t];
    float cnt = (float)(hi - lo);
    g1[g * CH + t] = selu_f(acc / fmaxf(cnt, 1.f));
}

// ---- head: selu(g1 @ fc1 + b1) @ fc2 + b2 -> log_softmax -------------------
__global__ __launch_bounds__(128) void head_kernel(
        const float* __restrict__ g1, const float* __restrict__ fc1W,
        const float* __restrict__ fc1b, const float* __restrict__ fc2W,
        const float* __restrict__ fc2b, float* __restrict__ out) {
    __shared__ float row[CH];
    __shared__ float hrow[HID];
    __shared__ float logits[2];
    int g = blockIdx.x, t = threadIdx.x;
    row[t] = g1[g * CH + t];
    row[t + 128] = g1[g * CH + t + 128];
    __syncthreads();
    float acc = fc1b[t];
    for (int k = 0; k < CH; k++) acc += row[k] * fc1W[k * HID + t];
    hrow[t] = selu_f(acc);
    __syncthreads();
    if (t < 2) {
        float a = fc2b[t];
        for (int k = 0; k < HID; k++) a += hrow[k] * fc2W[k * 2 + t];
        logits[t] = a;
    }
    __syncthreads();
    if (t < 2) {
        float m = fmaxf(logits[0], logits[1]);
        float lse = logf(expf(logits[0] - m) + expf(logits[1] - m)) + m;
        out[g * 2 + t] = logits[t] - lse;
    }
}

extern "C" void kernel_launch(void* const* d_in, const int* in_sizes, int n_in,
                              void* d_out, int out_size, void* d_ws, size_t ws_size,
                              hipStream_t stream) {
    const float* x      = (const float*)d_in[0];
    const int*   ei     = (const int*)d_in[1];
    const int*   batch  = (const int*)d_in[2];
    const float* W1     = (const float*)d_in[3];
    const float* att_l1 = (const float*)d_in[4];
    const float* att_r1 = (const float*)d_in[5];
    const float* b1     = (const float*)d_in[6];
    const float* W2     = (const float*)d_in[7];
    const float* att_l2 = (const float*)d_in[8];
    const float* att_r2 = (const float*)d_in[9];
    const float* b2     = (const float*)d_in[10];
    const float* fc1W   = (const float*)d_in[11];
    const float* fc1b   = (const float*)d_in[12];
    const float* fc2W   = (const float*)d_in[13];
    const float* fc2b   = (const float*)d_in[14];
    float* out = (float*)d_out;

    char* ws = (char*)d_ws;
    size_t off = 0;
    auto alloc = [&](size_t bytes) {
        void* p = ws + off;
        off += (bytes + 255) & ~(size_t)255;
        return p;
    };
    ushort_t* Ab     = (ushort_t*)alloc((size_t)N_NODES * KP1 * 2);   // x bf16 padded
    ushort_t* Hb1    = (ushort_t*)alloc((size_t)N_NODES * CH * 2);    // GEMM1 out (bf16)
    ushort_t* Zb2    = (ushort_t*)alloc((size_t)N_NODES * CH * 2);    // agg1 out (bf16)
    ushort_t* Hb2    = (ushort_t*)alloc((size_t)N_NODES * CH * 2);    // GEMM2 out (bf16)
    float*    hbuf   = (float*)alloc((size_t)N_NODES * CH * 4);       // agg2 out (f32)
    ushort_t* W1t    = (ushort_t*)alloc((size_t)CH * KP1 * 2);
    ushort_t* W2t    = (ushort_t*)alloc((size_t)CH * CH * 2);
    float*    a_src  = (float*)alloc((size_t)N_NODES * 4);
    float*    a_dst  = (float*)alloc((size_t)N_NODES * 4);
    int*      deg    = (int*)alloc((size_t)N_NODES * 4);
    int*      startA = (int*)alloc((size_t)N_NODES * 4);
    int*      fillpos= (int*)alloc((size_t)N_NODES * 4);
    int*      csr_src= (int*)alloc((size_t)N_TOT * 4);
    int*      cursor = (int*)alloc(256);
    float*    g1     = (float*)alloc((size_t)N_GRAPHS * CH * 4);

    dim3 blk(256);
    dim3 gemm_grid(CH / 128, (N_NODES + 127) / 128);
    int edge_grid = (N_TOT + 255) / 256;
    int node_grid = (N_NODES + 255) / 256;
    int agg_grid  = (int)(((long)N_NODES * 64 + 255) / 256);
    long xconv = (long)N_NODES * KP1;

    // ---------------- input conversions + CSR build ----------------
    convert_pad_x<<<(int)((xconv + 255) / 256), blk, 0, stream>>>(x, Ab);
    convert_wt<<<(CH * KP1 + 255) / 256, blk, 0, stream>>>(W1, W1t, F_IN, KP1);
    convert_wt<<<(CH * CH + 255) / 256, blk, 0, stream>>>(W2, W2t, CH, CH);
    hipMemsetAsync(deg, 0, (size_t)N_NODES * 4, stream);
    hipMemsetAsync(cursor, 0, 4, stream);
    deg_count<<<edge_grid, blk, 0, stream>>>(ei, deg);
    reserve_k<<<node_grid, blk, 0, stream>>>(deg, startA, fillpos, cursor, N_NODES);
    csr_fill<<<edge_grid, blk, 0, stream>>>(ei, fillpos, csr_src);

    // ---------------- Layer 1 ----------------
    hipMemsetAsync(a_src, 0, (size_t)N_NODES * 4, stream);
    hipMemsetAsync(a_dst, 0, (size_t)N_NODES * 4, stream);
    gemm_bf16_fused<<<gemm_grid, blk, 0, stream>>>(Ab, W1t, Hb1, att_l1, att_r1,
                                                   a_src, a_dst, N_NODES, KP1);
    gat_aggregate<<<agg_grid, blk, 0, stream>>>(startA, deg, csr_src, a_src, a_dst,
                                                Hb1, b1, (float*)nullptr, Zb2, N_NODES);

    // ---------------- Layer 2 ----------------
    hipMemsetAsync(a_src, 0, (size_t)N_NODES * 4, stream);
    hipMemsetAsync(a_dst, 0, (size_t)N_NODES * 4, stream);
    gemm_bf16_fused<<<gemm_grid, blk, 0, stream>>>(Zb2, W2t, Hb2, att_l2, att_r2,
                                                   a_src, a_dst, N_NODES, CH);
    gat_aggregate<<<agg_grid, blk, 0, stream>>>(startA, deg, csr_src, a_src, a_dst,
                                                Hb2, b2, hbuf, (ushort_t*)nullptr, N_NODES);

    // ---------------- Pool + head ----------------
    pool_kernel<<<N_GRAPHS, blk, 0, stream>>>(hbuf, batch, g1);
    head_kernel<<<N_GRAPHS, dim3(128), 0, stream>>>(g1, fc1W, fc1b, fc2W, fc2b, out);
}

// Round 5
// 399.243 us; speedup vs baseline: 5.6511x; 1.2354x over previous
//
#include <hip/hip_runtime.h>
#include <hip/hip_bf16.h>

#define N_NODES 50000
#define N_EDGES 800000
#define N_TOT   (N_EDGES + N_NODES)
#define N_GRAPHS 256
#define F_IN 310
#define KP1 320          // F_IN padded to multiple of 32
#define CH 256
#define HID 128
#define DEG_CAP 128      // per-wave LDS edge cache (avg deg ~17; P(deg>128) ~ 0)

typedef __attribute__((ext_vector_type(8))) short short8;
typedef __attribute__((ext_vector_type(4))) float f32x4;
typedef unsigned short ushort_t;

__device__ __forceinline__ float selu_f(float x) {
    const float scale = 1.0507009873554805f;
    const float alpha = 1.6732632423543772f;
    return x > 0.f ? scale * x : scale * alpha * (expm1f(x));
}

__device__ __forceinline__ ushort_t f32_to_bf16_rne(float f) {
    unsigned u = __float_as_uint(f);
    unsigned rounding = 0x7FFFu + ((u >> 16) & 1u);
    return (ushort_t)((u + rounding) >> 16);
}
__device__ __forceinline__ float bf16_to_f32(ushort_t v) {
    return __uint_as_float(((unsigned)v) << 16);
}

// ---- convert x [N, 310] f32 -> A [N, 320] bf16 (block per row) -------------
__global__ __launch_bounds__(256) void convert_pad_x(
        const float* __restrict__ x, ushort_t* __restrict__ A) {
    int r = blockIdx.x;
    const float* xr = x + (long)r * F_IN;
    ushort_t* Ar = A + (long)r * KP1;
    for (int c = threadIdx.x; c < KP1; c += 256)
        Ar[c] = (c < F_IN) ? f32_to_bf16_rne(xr[c]) : 0;
}

// ---- W [K, 256] f32 -> Wt [256, Kp] bf16 (transposed, zero-padded) ---------
__global__ __launch_bounds__(256) void convert_wt(
        const float* __restrict__ W, ushort_t* __restrict__ Wt, int K, int Kp) {
    int i = blockIdx.x * blockDim.x + threadIdx.x;
    if (i >= CH * Kp) return;
    int n = i / Kp, k = i % Kp;
    Wt[i] = (k < K) ? f32_to_bf16_rne(W[(long)k * CH + n]) : 0;
}

// ------- MFMA GEMM + fused attention-scalar epilogue ------------------------
__global__ __launch_bounds__(256) void gemm_bf16_fused(
        const ushort_t* __restrict__ A, const ushort_t* __restrict__ Bt,
        ushort_t* __restrict__ Cb, const float* __restrict__ att_l,
        const float* __restrict__ att_r, float* __restrict__ a_src,
        float* __restrict__ a_dst, int M, int Kp) {
    __shared__ __align__(16) ushort_t As[128 * 32];
    __shared__ __align__(16) ushort_t Bs[128 * 32];
    int tid = threadIdx.x;
    int col0 = blockIdx.x * 128;
    int row0 = blockIdx.y * 128;
    int w = tid >> 6, l = tid & 63;
    int lr = l & 15, lc = l >> 4;
    f32x4 acc[2][8] = {};
    int sr = tid >> 2;
    int sc = tid & 3;

    for (int k0 = 0; k0 < Kp; k0 += 32) {
#pragma unroll
        for (int i = 0; i < 2; i++) {
            int r = sr + i * 64;
            int grow = row0 + r;
            int4 av = {0, 0, 0, 0};
            if (grow < M) av = *(const int4*)(A + (size_t)grow * Kp + k0 + sc * 8);
            *(int4*)(As + r * 32 + ((sc ^ (r & 3)) * 8)) = av;
            int4 bv = *(const int4*)(Bt + (size_t)(col0 + r) * Kp + k0 + sc * 8);
            *(int4*)(Bs + r * 32 + ((sc ^ (r & 3)) * 8)) = bv;
        }
        __syncthreads();
        short8 af[2], bf[8];
#pragma unroll
        for (int mi = 0; mi < 2; mi++) {
            int r = w * 32 + mi * 16 + lr;
            af[mi] = *(const short8*)(As + r * 32 + ((lc ^ (r & 3)) * 8));
        }
#pragma unroll
        for (int ni = 0; ni < 8; ni++) {
            int r = ni * 16 + lr;
            bf[ni] = *(const short8*)(Bs + r * 32 + ((lc ^ (r & 3)) * 8));
        }
#pragma unroll
        for (int mi = 0; mi < 2; mi++)
#pragma unroll
            for (int ni = 0; ni < 8; ni++)
                acc[mi][ni] = __builtin_amdgcn_mfma_f32_16x16x32_bf16(
                    af[mi], bf[ni], acc[mi][ni], 0, 0, 0);
        __syncthreads();
    }
    float al[8], ar[8];
#pragma unroll
    for (int ni = 0; ni < 8; ni++) {
        int col = col0 + ni * 16 + lr;
        al[ni] = att_l[col];
        ar[ni] = att_r[col];
    }
#pragma unroll
    for (int mi = 0; mi < 2; mi++) {
        int rbase = row0 + w * 32 + mi * 16 + lc * 4;
#pragma unroll
        for (int q = 0; q < 4; q++) {
            int grow = rbase + q;
            float pl = 0.f, pr = 0.f;
#pragma unroll
            for (int ni = 0; ni < 8; ni++) {
                float v = acc[mi][ni][q];
                pl += v * al[ni];
                pr += v * ar[ni];
                if (grow < M) Cb[(size_t)grow * CH + col0 + ni * 16 + lr] = f32_to_bf16_rne(v);
            }
#pragma unroll
            for (int off = 1; off < 16; off <<= 1) {
                pl += __shfl_xor(pl, off);
                pr += __shfl_xor(pr, off);
            }
            if (lr == 0 && grow < M) {
                atomicAdd(&a_src[grow], pl);
                atomicAdd(&a_dst[grow], pr);
            }
        }
    }
}

// ---------------- CSR build: deg count -> range reserve -> fill -------------
__global__ __launch_bounds__(256) void deg_count(
        const int* __restrict__ ei, int* __restrict__ deg) {
    int eid = blockIdx.x * blockDim.x + threadIdx.x;
    if (eid >= N_TOT) return;
    int d = (eid < N_EDGES) ? ei[N_EDGES + eid] : eid - N_EDGES;
    atomicAdd(&deg[d], 1);
}

__global__ __launch_bounds__(256) void reserve_k(
        const int* __restrict__ deg, int* __restrict__ start,
        int* __restrict__ fillpos, int* __restrict__ cursor, int n) {
    int i = blockIdx.x * blockDim.x + threadIdx.x;
    if (i >= n) return;
    int s = atomicAdd(cursor, deg[i]);
    start[i] = s;
    fillpos[i] = s;
}

__global__ __launch_bounds__(256) void csr_fill(
        const int* __restrict__ ei, int* __restrict__ fillpos,
        int* __restrict__ csr_src) {
    int eid = blockIdx.x * blockDim.x + threadIdx.x;
    if (eid >= N_TOT) return;
    int s, d;
    if (eid < N_EDGES) { s = ei[eid]; d = ei[N_EDGES + eid]; }
    else { s = eid - N_EDGES; d = s; }
    int p = atomicAdd(&fillpos[d], 1);
    csr_src[p] = s;
}

// ---- fused per-dst softmax + bf16 gather-accumulate, LDS edge cache --------
// one wave per node (4 waves/block); (src, e/alpha-num) stashed in LDS so the
// gather pass does no exp/reload and runs 4 h-row gathers in flight.
__global__ __launch_bounds__(256) void gat_aggregate(
        const int* __restrict__ start, const int* __restrict__ deg,
        const int* __restrict__ csr_src,
        const float* __restrict__ a_src, const float* __restrict__ a_dst,
        const ushort_t* __restrict__ h, const float* __restrict__ bias,
        float* __restrict__ out_f32, ushort_t* __restrict__ out_bf, int n) {
    __shared__ int   s_idx[4][DEG_CAP];
    __shared__ float s_ex[4][DEG_CAP];
    int wid = threadIdx.x >> 6;
    int lane = threadIdx.x & 63;
    int node = blockIdx.x * 4 + wid;
    if (node >= n) return;
    int s0 = start[node];
    int dg = deg[node];
    float ad = a_dst[node];
    bool cached = (dg <= DEG_CAP);

    // sweep 1: compute e per edge once, stash (s, e) in LDS; lane max
    float m = -1e30f;
    for (int i = lane; i < dg; i += 64) {
        int s = csr_src[s0 + i];
        float e = a_src[s] + ad;
        e = e > 0.f ? e : 0.2f * e;
        if (cached) { s_idx[wid][i] = s; s_ex[wid][i] = e; }
        m = fmaxf(m, e);
    }
#pragma unroll
    for (int off = 32; off > 0; off >>= 1) m = fmaxf(m, __shfl_xor(m, off));

    // sweep 2: e -> exp(e-m) in LDS; lane sum
    float sum = 0.f;
    if (cached) {
        for (int i = lane; i < dg; i += 64) {
            float ex = __expf(s_ex[wid][i] - m);
            s_ex[wid][i] = ex;
            sum += ex;
        }
    } else {
        for (int i = lane; i < dg; i += 64) {
            int s = csr_src[s0 + i];
            float e = a_src[s] + ad;
            e = e > 0.f ? e : 0.2f * e;
            sum += __expf(e - m);
        }
    }
#pragma unroll
    for (int off = 32; off > 0; off >>= 1) sum += __shfl_xor(sum, off);
    float inv = 1.f / fmaxf(sum, 1e-16f);

    // pass 3: alpha from LDS; 4 gathers in flight
    float4 acc = {0.f, 0.f, 0.f, 0.f};
    if (cached) {
        int i = 0;
        for (; i + 4 <= dg; i += 4) {
            int sa = s_idx[wid][i],     sb = s_idx[wid][i + 1];
            int sc_ = s_idx[wid][i + 2], sd = s_idx[wid][i + 3];
            float xa = s_ex[wid][i] * inv,     xb = s_ex[wid][i + 1] * inv;
            float xc = s_ex[wid][i + 2] * inv, xd = s_ex[wid][i + 3] * inv;
            ushort4 ha = *(const ushort4*)(h + (long)sa * CH + lane * 4);
            ushort4 hb = *(const ushort4*)(h + (long)sb * CH + lane * 4);
            ushort4 hc = *(const ushort4*)(h + (long)sc_ * CH + lane * 4);
            ushort4 hd = *(const ushort4*)(h + (long)sd * CH + lane * 4);
            acc.x += xa * bf16_to_f32(ha.x) + xb * bf16_to_f32(hb.x)
                   + xc * bf16_to_f32(hc.x) + xd * bf16_to_f32(hd.x);
            acc.y += xa * bf16_to_f32(ha.y) + xb * bf16_to_f32(hb.y)
                   + xc * bf16_to_f32(hc.y) + xd * bf16_to_f32(hd.y);
            acc.z += xa * bf16_to_f32(ha.z) + xb * bf16_to_f32(hb.z)
                   + xc * bf16_to_f32(hc.z) + xd * bf16_to_f32(hd.z);
            acc.w += xa * bf16_to_f32(ha.w) + xb * bf16_to_f32(hb.w)
                   + xc * bf16_to_f32(hc.w) + xd * bf16_to_f32(hd.w);
        }
        for (; i < dg; i++) {
            int s = s_idx[wid][i];
            float xa = s_ex[wid][i] * inv;
            ushort4 hv = *(const ushort4*)(h + (long)s * CH + lane * 4);
            acc.x += xa * bf16_to_f32(hv.x);
            acc.y += xa * bf16_to_f32(hv.y);
            acc.z += xa * bf16_to_f32(hv.z);
            acc.w += xa * bf16_to_f32(hv.w);
        }
    } else {
        for (int i = 0; i < dg; i++) {
            int s = csr_src[s0 + i];
            float e = a_src[s] + ad;
            e = e > 0.f ? e : 0.2f * e;
            float alpha = __expf(e - m) * inv;
            ushort4 hv = *(const ushort4*)(h + (long)s * CH + lane * 4);
            acc.x += alpha * bf16_to_f32(hv.x);
            acc.y += alpha * bf16_to_f32(hv.y);
            acc.z += alpha * bf16_to_f32(hv.z);
            acc.w += alpha * bf16_to_f32(hv.w);
        }
    }
    float4 bv = *(const float4*)(bias + lane * 4);
    float4 o;
    o.x = selu_f(acc.x + bv.x);
    o.y = selu_f(acc.y + bv.y);
    o.z = selu_f(acc.z + bv.z);
    o.w = selu_f(acc.w + bv.w);
    if (out_f32) *(float4*)(out_f32 + (long)node * CH + lane * 4) = o;
    if (out_bf) {
        ushort4 ob;
        ob.x = f32_to_bf16_rne(o.x);
        ob.y = f32_to_bf16_rne(o.y);
        ob.z = f32_to_bf16_rne(o.z);
        ob.w = f32_to_bf16_rne(o.w);
        *(ushort4*)(out_bf + (long)node * CH + lane * 4) = ob;
    }
}

// ---- pool: batch is SORTED -> per-graph segment via binary search ----------
__global__ __launch_bounds__(256) void pool_kernel(
        const float* __restrict__ h, const int* __restrict__ batch,
        float* __restrict__ g1) {
    int g = blockIdx.x;
    int t = threadIdx.x;
    int lo, hi;
    { int a = 0, b = N_NODES;
      while (a < b) { int mid = (a + b) >> 1; if (batch[mid] < g) a = mid + 1; else b = mid; }
      lo = a; }
    { int a = lo, b = N_NODES;
      while (a < b) { int mid = (a + b) >> 1; if (batch[mid] < g + 1) a = mid + 1; else b = mid; }
      hi = a; }
    float acc = 0.f;
    for (int i = lo; i < hi; i++) acc += h[(long)i * CH + t];
    float cnt = (float)(hi - lo);
    g1[g * CH + t] = selu_f(acc / fmaxf(cnt, 1.f));
}

// ---- head: selu(g1 @ fc1 + b1) @ fc2 + b2 -> log_softmax -------------------
__global__ __launch_bounds__(128) void head_kernel(
        const float* __restrict__ g1, const float* __restrict__ fc1W,
        const float* __restrict__ fc1b, const float* __restrict__ fc2W,
        const float* __restrict__ fc2b, float* __restrict__ out) {
    __shared__ float row[CH];
    __shared__ float hrow[HID];
    __shared__ float logits[2];
    int g = blockIdx.x, t = threadIdx.x;
    row[t] = g1[g * CH + t];
    row[t + 128] = g1[g * CH + t + 128];
    __syncthreads();
    float acc = fc1b[t];
    for (int k = 0; k < CH; k++) acc += row[k] * fc1W[k * HID + t];
    hrow[t] = selu_f(acc);
    __syncthreads();
    if (t < 2) {
        float a = fc2b[t];
        for (int k = 0; k < HID; k++) a += hrow[k] * fc2W[k * 2 + t];
        logits[t] = a;
    }
    __syncthreads();
    if (t < 2) {
        float m = fmaxf(logits[0], logits[1]);
        float lse = logf(expf(logits[0] - m) + expf(logits[1] - m)) + m;
        out[g * 2 + t] = logits[t] - lse;
    }
}

extern "C" void kernel_launch(void* const* d_in, const int* in_sizes, int n_in,
                              void* d_out, int out_size, void* d_ws, size_t ws_size,
                              hipStream_t stream) {
    const float* x      = (const float*)d_in[0];
    const int*   ei     = (const int*)d_in[1];
    const int*   batch  = (const int*)d_in[2];
    const float* W1     = (const float*)d_in[3];
    const float* att_l1 = (const float*)d_in[4];
    const float* att_r1 = (const float*)d_in[5];
    const float* b1     = (const float*)d_in[6];
    const float* W2     = (const float*)d_in[7];
    const float* att_l2 = (const float*)d_in[8];
    const float* att_r2 = (const float*)d_in[9];
    const float* b2     = (const float*)d_in[10];
    const float* fc1W   = (const float*)d_in[11];
    const float* fc1b   = (const float*)d_in[12];
    const float* fc2W   = (const float*)d_in[13];
    const float* fc2b   = (const float*)d_in[14];
    float* out = (float*)d_out;

    char* ws = (char*)d_ws;
    size_t off = 0;
    auto alloc = [&](size_t bytes) {
        void* p = ws + off;
        off += (bytes + 255) & ~(size_t)255;
        return p;
    };
    ushort_t* Ab     = (ushort_t*)alloc((size_t)N_NODES * KP1 * 2);
    ushort_t* Hb1    = (ushort_t*)alloc((size_t)N_NODES * CH * 2);
    ushort_t* Zb2    = (ushort_t*)alloc((size_t)N_NODES * CH * 2);
    ushort_t* Hb2    = (ushort_t*)alloc((size_t)N_NODES * CH * 2);
    float*    hbuf   = (float*)alloc((size_t)N_NODES * CH * 4);
    ushort_t* W1t    = (ushort_t*)alloc((size_t)CH * KP1 * 2);
    ushort_t* W2t    = (ushort_t*)alloc((size_t)CH * CH * 2);
    float*    a_src  = (float*)alloc((size_t)N_NODES * 4);
    float*    a_dst  = (float*)alloc((size_t)N_NODES * 4);
    int*      deg    = (int*)alloc((size_t)N_NODES * 4);
    int*      startA = (int*)alloc((size_t)N_NODES * 4);
    int*      fillpos= (int*)alloc((size_t)N_NODES * 4);
    int*      csr_src= (int*)alloc((size_t)N_TOT * 4);
    int*      cursor = (int*)alloc(256);
    float*    g1     = (float*)alloc((size_t)N_GRAPHS * CH * 4);

    dim3 blk(256);
    dim3 gemm_grid(CH / 128, (N_NODES + 127) / 128);
    int edge_grid = (N_TOT + 255) / 256;
    int node_grid = (N_NODES + 255) / 256;
    int agg_grid  = (N_NODES + 3) / 4;

    // ---------------- input conversions + CSR build ----------------
    convert_pad_x<<<N_NODES, blk, 0, stream>>>(x, Ab);
    convert_wt<<<(CH * KP1 + 255) / 256, blk, 0, stream>>>(W1, W1t, F_IN, KP1);
    convert_wt<<<(CH * CH + 255) / 256, blk, 0, stream>>>(W2, W2t, CH, CH);
    hipMemsetAsync(deg, 0, (size_t)N_NODES * 4, stream);
    hipMemsetAsync(cursor, 0, 4, stream);
    deg_count<<<edge_grid, blk, 0, stream>>>(ei, deg);
    reserve_k<<<node_grid, blk, 0, stream>>>(deg, startA, fillpos, cursor, N_NODES);
    csr_fill<<<edge_grid, blk, 0, stream>>>(ei, fillpos, csr_src);

    // ---------------- Layer 1 ----------------
    hipMemsetAsync(a_src, 0, (size_t)N_NODES * 4, stream);
    hipMemsetAsync(a_dst, 0, (size_t)N_NODES * 4, stream);
    gemm_bf16_fused<<<gemm_grid, blk, 0, stream>>>(Ab, W1t, Hb1, att_l1, att_r1,
                                                   a_src, a_dst, N_NODES, KP1);
    gat_aggregate<<<agg_grid, blk, 0, stream>>>(startA, deg, csr_src, a_src, a_dst,
                                                Hb1, b1, (float*)nullptr, Zb2, N_NODES);

    // ---------------- Layer 2 ----------------
    hipMemsetAsync(a_src, 0, (size_t)N_NODES * 4, stream);
    hipMemsetAsync(a_dst, 0, (size_t)N_NODES * 4, stream);
    gemm_bf16_fused<<<gemm_grid, blk, 0, stream>>>(Zb2, W2t, Hb2, att_l2, att_r2,
                                                   a_src, a_dst, N_NODES, CH);
    gat_aggregate<<<agg_grid, blk, 0, stream>>>(startA, deg, csr_src, a_src, a_dst,
                                                Hb2, b2, hbuf, (ushort_t*)nullptr, N_NODES);

    // ---------------- Pool + head ----------------
    pool_kernel<<<N_GRAPHS, blk, 0, stream>>>(hbuf, batch, g1);
    head_kernel<<<N_GRAPHS, dim3(128), 0, stream>>>(g1, fc1W, fc1b, fc2W, fc2b, out);
}